// Round 1
// baseline (6789.342 us; speedup 1.0000x reference)
//
#include <hip/hip_runtime.h>
#include <hip/hip_bf16.h>

// Sizes (fixed by the problem)
#define B_   512
#define L_   64
#define D_   16
#define H_   256
#define V_   512
#define STEPS_ 64
// dt = 63/64 exactly
#define DT_  0.984375f

// ---------------- prep kernels ----------------

// generic transpose: src is R x C row-major; dst is C x R with dst[c*R+r]=src[r*C+c]
__global__ void transpose_kernel(const float* __restrict__ src, float* __restrict__ dst,
                                 int R, int C) {
    int idx = blockIdx.x * 256 + threadIdx.x;
    if (idx < R * C) {
        int r = idx / C, c = idx % C;
        dst[c * R + r] = src[idx];
    }
}

// dXall[s][b][d] for all 64 steps: spline derivative at t = s*63/64
__global__ void spline_kernel(const float* __restrict__ coeffs, float* __restrict__ dXall) {
    int idx = blockIdx.x * 256 + threadIdx.x;   // 64*512*16 = 524288 total
    int d = idx & 15;
    int b = (idx >> 4) & 511;
    int s = idx >> 13;
    float t = (float)s * (63.0f / 64.0f);
    int ii = (int)floorf(t);
    ii = min(max(ii, 0), L_ - 2);
    float frac = t - (float)ii;
    // coeffs[b, ii, j, d] at ((b*63 + ii)*4 + j)*16 + d
    const float* cb = coeffs + ((b * (L_ - 1) + ii) * 4) * 16 + d;
    float c1 = cb[16], c2 = cb[32], c3 = cb[48];
    dXall[idx] = c1 + 2.0f * frac * c2 + 3.0f * frac * frac * c3;
}

// h0 = tanh(X0 @ W0^T + b0); X0[b,d] = coeffs[b,0,0,d]
__global__ void h0_kernel(const float* __restrict__ coeffs, const float* __restrict__ W0,
                          const float* __restrict__ b0, float* __restrict__ h) {
    int b = blockIdx.x;
    int hh = threadIdx.x;     // 256
    float acc = b0[hh];
    #pragma unroll
    for (int d = 0; d < 16; d++)
        acc += coeffs[b * ((L_ - 1) * 4 * D_) + d] * W0[hh * 16 + d];
    h[b * H_ + hh] = tanhf(acc);
}

// ---------------- per-step kernels ----------------

// Fused: z1 = LN(tanh(h @ W1^T + b1)); z2 = LN(tanh(z1 @ W2^T + b2))
// block = 256 threads (4 waves), handles 4 batch rows, full V=512 columns.
__global__ __launch_bounds__(256) void mlp12_kernel(
    const float* __restrict__ h, const float* __restrict__ W1T, const float* __restrict__ b1,
    const float* __restrict__ g1, const float* __restrict__ be1,
    const float* __restrict__ W2T, const float* __restrict__ b2,
    const float* __restrict__ g2, const float* __restrict__ be2,
    float* __restrict__ z2out)
{
    __shared__ float hs[4][H_];      // 4 KB
    __shared__ float z1s[4][V_];     // 8 KB
    __shared__ float z2s[4][V_];     // 8 KB
    const int tid = threadIdx.x;
    const int b0r = blockIdx.x * 4;

    for (int i = tid; i < 4 * H_; i += 256)
        hs[i >> 8][i & 255] = h[(b0r + (i >> 8)) * H_ + (i & 255)];
    __syncthreads();

    // ---- stage 1: K=256 rank-1 updates, thread owns cols {tid, tid+256} ----
    float a0[4] = {0, 0, 0, 0}, a1[4] = {0, 0, 0, 0};
    for (int k = 0; k < H_; k++) {
        float wa = W1T[k * V_ + tid];
        float wb = W1T[k * V_ + 256 + tid];
        #pragma unroll
        for (int r = 0; r < 4; r++) {
            float hk = hs[r][k];
            a0[r] += wa * hk;
            a1[r] += wb * hk;
        }
    }
    {
        float ba = b1[tid], bb = b1[tid + 256];
        #pragma unroll
        for (int r = 0; r < 4; r++) {
            z1s[r][tid]       = tanhf(a0[r] + ba);
            z1s[r][tid + 256] = tanhf(a1[r] + bb);
        }
    }
    __syncthreads();

    const int wave = tid >> 6, lane = tid & 63;
    // ---- LN row `wave` ----
    {
        float v[8], s = 0.f, ss = 0.f;
        #pragma unroll
        for (int j = 0; j < 8; j++) {
            v[j] = z1s[wave][lane + j * 64];
            s += v[j]; ss += v[j] * v[j];
        }
        #pragma unroll
        for (int o = 32; o; o >>= 1) { s += __shfl_xor(s, o); ss += __shfl_xor(ss, o); }
        float m = s * (1.f / 512.f);
        float var = ss * (1.f / 512.f) - m * m;
        float rstd = rsqrtf(var + 1e-5f);
        #pragma unroll
        for (int j = 0; j < 8; j++) {
            int c = lane + j * 64;
            z1s[wave][c] = (v[j] - m) * rstd * g1[c] + be1[c];
        }
    }
    __syncthreads();

    // ---- stage 2: K=512 ----
    float c0[4] = {0, 0, 0, 0}, c1r[4] = {0, 0, 0, 0};
    for (int k = 0; k < V_; k++) {
        float wa = W2T[k * V_ + tid];
        float wb = W2T[k * V_ + 256 + tid];
        #pragma unroll
        for (int r = 0; r < 4; r++) {
            float zk = z1s[r][k];
            c0[r]  += wa * zk;
            c1r[r] += wb * zk;
        }
    }
    {
        float ba = b2[tid], bb = b2[tid + 256];
        #pragma unroll
        for (int r = 0; r < 4; r++) {
            z2s[r][tid]       = tanhf(c0[r] + ba);
            z2s[r][tid + 256] = tanhf(c1r[r] + bb);
        }
    }
    __syncthreads();
    // ---- LN row `wave`, write to global ----
    {
        float v[8], s = 0.f, ss = 0.f;
        #pragma unroll
        for (int j = 0; j < 8; j++) {
            v[j] = z2s[wave][lane + j * 64];
            s += v[j]; ss += v[j] * v[j];
        }
        #pragma unroll
        for (int o = 32; o; o >>= 1) { s += __shfl_xor(s, o); ss += __shfl_xor(ss, o); }
        float m = s * (1.f / 512.f);
        float var = ss * (1.f / 512.f) - m * m;
        float rstd = rsqrtf(var + 1e-5f);
        #pragma unroll
        for (int j = 0; j < 8; j++) {
            int c = lane + j * 64;
            z2out[(b0r + wave) * V_ + c] = (v[j] - m) * rstd * g2[c] + be2[c];
        }
    }
}

// vf = z2 @ W3^T + b3 (tile 64 rows x 128 cols, K=512 chunked through LDS),
// then h[b,hh] += dt * sum_d vf[b,hh*16+d] * dX[b,d]  (block-local, no atomics)
__global__ __launch_bounds__(256) void stage3_kernel(
    const float* __restrict__ z2, const float* __restrict__ W3T,
    const float* __restrict__ b3, const float* __restrict__ dX,
    float* __restrict__ h)
{
    __shared__ float zs[64][128];    // 32 KB  (z2 K-chunk)
    __shared__ float dxs[64][16];    // 4 KB
    __shared__ float vfs[64][128];   // 32 KB
    const int tid = threadIdx.x;
    const int row0 = blockIdx.x * 64;   // 8 row-blocks
    const int col0 = blockIdx.y * 128;  // 32 col-blocks
    const int tx = tid & 31, ty = tid >> 5;   // 32 x 8

    for (int i = tid; i < 64 * 16; i += 256)
        dxs[i >> 4][i & 15] = dX[(row0 + (i >> 4)) * 16 + (i & 15)];

    float acc[8][4];
    #pragma unroll
    for (int i = 0; i < 8; i++)
        #pragma unroll
        for (int j = 0; j < 4; j++) acc[i][j] = 0.f;

    for (int kc = 0; kc < V_; kc += 128) {
        __syncthreads();
        for (int i = tid; i < 64 * 128; i += 256)
            zs[i >> 7][i & 127] = z2[(row0 + (i >> 7)) * V_ + kc + (i & 127)];
        __syncthreads();
        for (int k = 0; k < 128; k++) {
            const float* wrow = W3T + (size_t)(kc + k) * 4096 + col0 + tx;
            float w0v = wrow[0], w1v = wrow[32], w2v = wrow[64], w3v = wrow[96];
            #pragma unroll
            for (int i = 0; i < 8; i++) {
                float zv = zs[ty * 8 + i][k];
                acc[i][0] += zv * w0v;
                acc[i][1] += zv * w1v;
                acc[i][2] += zv * w2v;
                acc[i][3] += zv * w3v;
            }
        }
    }
    __syncthreads();
    {
        float bw[4];
        #pragma unroll
        for (int j = 0; j < 4; j++) bw[j] = b3[col0 + tx + j * 32];
        #pragma unroll
        for (int i = 0; i < 8; i++)
            #pragma unroll
            for (int j = 0; j < 4; j++)
                vfs[ty * 8 + i][tx + j * 32] = acc[i][j] + bw[j];
    }
    __syncthreads();
    // h update: 64 rows x 8 local hh groups
    for (int o = tid; o < 64 * 8; o += 256) {
        int r = o >> 3, hl = o & 7;
        float s2 = 0.f;
        #pragma unroll
        for (int d = 0; d < 16; d++) s2 += vfs[r][hl * 16 + d] * dxs[r][d];
        int hh = (col0 >> 4) + hl;
        h[(row0 + r) * H_ + hh] += s2 * DT_;
    }
}

// ---------------- launch ----------------

extern "C" void kernel_launch(void* const* d_in, const int* in_sizes, int n_in,
                              void* d_out, int out_size, void* d_ws, size_t ws_size,
                              hipStream_t stream) {
    const float* coeffs = (const float*)d_in[0];
    const float* W0  = (const float*)d_in[1];
    const float* b0  = (const float*)d_in[2];
    const float* W1  = (const float*)d_in[3];
    const float* b1  = (const float*)d_in[4];
    const float* g1  = (const float*)d_in[5];
    const float* be1 = (const float*)d_in[6];
    const float* W2  = (const float*)d_in[7];
    const float* b2  = (const float*)d_in[8];
    const float* g2  = (const float*)d_in[9];
    const float* be2 = (const float*)d_in[10];
    const float* W3  = (const float*)d_in[11];
    const float* b3  = (const float*)d_in[12];

    float* ws = (float*)d_ws;
    float* h     = ws;                 // 512*256          = 131072
    float* z2    = ws + 131072;        // 512*512          = 262144
    float* W1T   = ws + 393216;        // 256*512          = 131072
    float* W2T   = ws + 524288;        // 512*512          = 262144
    float* W3T   = ws + 786432;        // 512*4096         = 2097152
    float* dXall = ws + 2883584;       // 64*512*16        = 524288
    // total 3407872 floats = 13 MB

    transpose_kernel<<<(V_ * H_ + 255) / 256, 256, 0, stream>>>(W1, W1T, V_, H_);
    transpose_kernel<<<(V_ * V_ + 255) / 256, 256, 0, stream>>>(W2, W2T, V_, V_);
    transpose_kernel<<<(4096 * V_ + 255) / 256, 256, 0, stream>>>(W3, W3T, 4096, V_);
    spline_kernel<<<(STEPS_ * B_ * D_) / 256, 256, 0, stream>>>(coeffs, dXall);
    h0_kernel<<<B_, H_, 0, stream>>>(coeffs, W0, b0, h);

    for (int s = 0; s < STEPS_; s++) {
        mlp12_kernel<<<B_ / 4, 256, 0, stream>>>(h, W1T, b1, g1, be1,
                                                 W2T, b2, g2, be2, z2);
        stage3_kernel<<<dim3(8, 32), 256, 0, stream>>>(z2, W3T, b3,
                                                       dXall + s * (B_ * D_), h);
    }

    hipMemcpyAsync(d_out, h, (size_t)B_ * H_ * sizeof(float),
                   hipMemcpyDeviceToDevice, stream);
}

// Round 3
// 2288.306 us; speedup vs baseline: 2.9670x; 2.9670x over previous
//
#include <hip/hip_runtime.h>
#include <hip/hip_bf16.h>

#define B_   512
#define L_   64
#define D_   16
#define H_   256
#define V_   512
#define STEPS_ 64
#define DT_  0.984375f
#define LOSC 2048.0f          // lo-term scale 2^11
#define LOSC_INV (1.0f/2048.0f)

typedef _Float16 half_t;
typedef __attribute__((ext_vector_type(8))) _Float16 half8;
typedef __attribute__((ext_vector_type(4))) float f32x4;

__device__ __forceinline__ void split16(float x, half_t& hi, half_t& lo) {
    half_t h = (half_t)x;
    hi = h;
    lo = (half_t)((x - (float)h) * LOSC);
}

// ---------------- prep kernels ----------------

// Pack W [N][K] fp32 into MFMA B-fragment order, f16 hi + scaled-lo:
// slot idx = ((g*Kc + c)*64 + l)*8 + j  <-  W[g*16 + (l&15)][c*32 + (l>>4)*8 + j]
__global__ void pack_frag_kernel(const float* __restrict__ src, half_t* __restrict__ hi,
                                 half_t* __restrict__ lo, int Kc, int K, int total) {
    int idx = blockIdx.x * 256 + threadIdx.x;
    if (idx >= total) return;
    int j = idx & 7;
    int l = (idx >> 3) & 63;
    int gc = idx >> 9;
    int c = gc % Kc, g = gc / Kc;
    int n = (g << 4) + (l & 15);
    int k = (c << 5) + ((l >> 4) << 3) + j;
    float w = src[n * K + k];
    half_t h, lw;
    split16(w, h, lw);
    hi[idx] = h;
    lo[idx] = lw;
}

// h0 = tanh(X0 @ W0^T + b0)
__global__ void h0_kernel(const float* __restrict__ coeffs, const float* __restrict__ W0,
                          const float* __restrict__ b0, float* __restrict__ hout) {
    int b = blockIdx.x;
    int hh = threadIdx.x;
    float acc = b0[hh];
    #pragma unroll
    for (int d = 0; d < 16; d++)
        acc += coeffs[b * ((L_ - 1) * 4 * D_) + d] * W0[hh * 16 + d];
    hout[b * H_ + hh] = tanhf(acc);
}

// ---------------- per-step kernels ----------------

// GEMM1: t1 = tanh(h @ W1^T + b1) -> packed f16 hi/lo A-fragments (Kc_out=16).
// Block 32 rows x 64 cols, 512 threads (8 waves). Grid (16, 8).
__global__ __launch_bounds__(512) void gemm1_kernel(
    const float* __restrict__ hptr,
    const half_t* __restrict__ W1h, const half_t* __restrict__ W1l,
    const float* __restrict__ b1,
    half_t* __restrict__ t1h, half_t* __restrict__ t1l)
{
    __shared__ __align__(16) half_t Ah[2 * 8 * 64 * 8];   // 16 KB
    __shared__ __align__(16) half_t Al[2 * 8 * 64 * 8];   // 16 KB
    __shared__ float zs[32][65];                          // 8.3 KB
    const int tid = threadIdx.x, w = tid >> 6, l = tid & 63;
    const int row0 = blockIdx.x * 32, col0 = blockIdx.y * 64;

    // prologue: stage h rows as f16 hi/lo fragments
    {
        int gm = w & 1;
        #pragma unroll
        for (int cc = 0; cc < 2; cc++) {
            int c = ((w >> 1) << 1) + cc;
            const float* src = hptr + (row0 + (gm << 4) + (l & 15)) * H_ + (c << 5) + ((l >> 4) << 3);
            float4 x = *(const float4*)src;
            float4 y = *(const float4*)(src + 4);
            float xx[8] = {x.x, x.y, x.z, x.w, y.x, y.y, y.z, y.w};
            half8 hv, lv;
            #pragma unroll
            for (int j = 0; j < 8; j++) { half_t a, b; split16(xx[j], a, b); hv[j] = a; lv[j] = b; }
            int base = (((gm << 3) + c) * 64 + l) * 8;
            *(half8*)&Ah[base] = hv;
            *(half8*)&Al[base] = lv;
        }
    }
    __syncthreads();

    const int mf = w & 1, nf = w >> 1;     // wave = (m-frag, n-frag)
    const int gn = (col0 >> 4) + nf;
    f32x4 acc = {0.f, 0.f, 0.f, 0.f}, accl = {0.f, 0.f, 0.f, 0.f};
    for (int c = 0; c < 8; c++) {
        half8 ah = *(const half8*)&Ah[(((mf << 3) + c) * 64 + l) * 8];
        half8 al = *(const half8*)&Al[(((mf << 3) + c) * 64 + l) * 8];
        half8 bh = *(const half8*)&W1h[(((gn << 3) + c) * 64 + l) * 8];
        half8 bl = *(const half8*)&W1l[(((gn << 3) + c) * 64 + l) * 8];
        acc  = __builtin_amdgcn_mfma_f32_16x16x32_f16(ah, bh, acc,  0, 0, 0);
        accl = __builtin_amdgcn_mfma_f32_16x16x32_f16(ah, bl, accl, 0, 0, 0);
        accl = __builtin_amdgcn_mfma_f32_16x16x32_f16(al, bh, accl, 0, 0, 0);
    }
    {
        int colb = (nf << 4) + (l & 15);
        float bb = b1[col0 + colb];
        #pragma unroll
        for (int j = 0; j < 4; j++) {
            float v = acc[j] + accl[j] * LOSC_INV + bb;
            zs[(mf << 4) + ((l >> 4) << 2) + j][colb] = tanhf(v);
        }
    }
    __syncthreads();
    // pack tanh output into next-stage A-fragments
    if (tid < 256) {
        int p = tid >> 6;              // 0..3 : (gm' 2) x (c' 2)
        int gmp = p & 1, cp = p >> 1;
        half8 hv, lv;
        #pragma unroll
        for (int j = 0; j < 8; j++) {
            float v = zs[(gmp << 4) + (l & 15)][(cp << 5) + ((l >> 4) << 3) + j];
            half_t a, b; split16(v, a, b); hv[j] = a; lv[j] = b;
        }
        int base = ((((row0 >> 4) + gmp) * 16 + (col0 >> 5) + cp) * 64 + l) * 8;
        *(half8*)&t1h[base] = hv;
        *(half8*)&t1l[base] = lv;
    }
}

// GEMM2: t2 = tanh(LN1(t1) @ W2^T + b2) -> packed fragments.
// LN1 stats computed in-block (full K=512 rows present).
// Block 32 rows x 64 cols, 512 threads. Grid (16, 8).
__global__ __launch_bounds__(512) void gemm2_kernel(
    const half_t* __restrict__ t1h, const half_t* __restrict__ t1l,
    const float* __restrict__ g1, const float* __restrict__ be1,
    const half_t* __restrict__ W2h, const half_t* __restrict__ W2l,
    const float* __restrict__ b2,
    half_t* __restrict__ t2h, half_t* __restrict__ t2l)
{
    __shared__ __align__(16) half_t Ah[2 * 16 * 64 * 8];  // 32 KB
    __shared__ __align__(16) half_t Al[2 * 16 * 64 * 8];  // 32 KB
    __shared__ float part[1024];                          // 4 KB
    __shared__ float mr[32], rrs[32];
    const int tid = threadIdx.x, w = tid >> 6, l = tid & 63;
    const int row0 = blockIdx.x * 32, col0 = blockIdx.y * 64;
    const int gm = w & 1, cbase = (w >> 1) << 2;

    // pass 1: reconstruct t1 values (kept in regs), row stats
    float tv[32];
    {
        float s = 0.f, ss = 0.f;
        #pragma unroll
        for (int cc = 0; cc < 4; cc++) {
            int c = cbase + cc;
            int base = ((((row0 >> 4) + gm) * 16 + c) * 64 + l) * 8;
            half8 hv = *(const half8*)&t1h[base];
            half8 lv = *(const half8*)&t1l[base];
            #pragma unroll
            for (int j = 0; j < 8; j++) {
                float t = (float)hv[j] + (float)lv[j] * LOSC_INV;
                tv[(cc << 3) + j] = t;
                s += t; ss += t * t;
            }
        }
        part[w * 64 + l] = s;
        part[512 + w * 64 + l] = ss;
    }
    __syncthreads();
    if (tid < 32) {
        int r = tid, rgm = r >> 4;
        float s = 0.f, ss = 0.f;
        #pragma unroll
        for (int wi = 0; wi < 4; wi++) {
            int wv = rgm + (wi << 1);
            #pragma unroll
            for (int u = 0; u < 4; u++) {
                int idx = wv * 64 + (r & 15) + (u << 4);
                s += part[idx]; ss += part[512 + idx];
            }
        }
        float m = s * (1.f / 512.f);
        float var = ss * (1.f / 512.f) - m * m;
        mr[r] = m;
        rrs[r] = rsqrtf(var + 1e-5f);
    }
    __syncthreads();
    // pass 2: normalize + split into LDS fragments
    {
        int row = (gm << 4) + (l & 15);
        float m = mr[row], rv = rrs[row];
        #pragma unroll
        for (int cc = 0; cc < 4; cc++) {
            int c = cbase + cc;
            half8 hv, lv;
            #pragma unroll
            for (int j = 0; j < 8; j++) {
                int k = (c << 5) + ((l >> 4) << 3) + j;
                float val = (tv[(cc << 3) + j] - m) * rv * g1[k] + be1[k];
                half_t a, b; split16(val, a, b); hv[j] = a; lv[j] = b;
            }
            int base = (((gm << 4) + c) * 64 + l) * 8;
            *(half8*)&Ah[base] = hv;
            *(half8*)&Al[base] = lv;
        }
    }
    __syncthreads();

    const int mf = w & 1, nf = w >> 1;
    const int gn = (col0 >> 4) + nf;
    f32x4 acc = {0.f, 0.f, 0.f, 0.f}, accl = {0.f, 0.f, 0.f, 0.f};
    for (int c = 0; c < 16; c++) {
        half8 ah = *(const half8*)&Ah[(((mf << 4) + c) * 64 + l) * 8];
        half8 al = *(const half8*)&Al[(((mf << 4) + c) * 64 + l) * 8];
        half8 bh = *(const half8*)&W2h[(((gn << 4) + c) * 64 + l) * 8];
        half8 bl = *(const half8*)&W2l[(((gn << 4) + c) * 64 + l) * 8];
        acc  = __builtin_amdgcn_mfma_f32_16x16x32_f16(ah, bh, acc,  0, 0, 0);
        accl = __builtin_amdgcn_mfma_f32_16x16x32_f16(ah, bl, accl, 0, 0, 0);
        accl = __builtin_amdgcn_mfma_f32_16x16x32_f16(al, bh, accl, 0, 0, 0);
    }
    __syncthreads();                       // main loop done -> Ah reusable as zs
    float (*zs)[65] = (float(*)[65])Ah;    // 8.3 KB overlay
    {
        int colb = (nf << 4) + (l & 15);
        float bb = b2[col0 + colb];
        #pragma unroll
        for (int j = 0; j < 4; j++) {
            float v = acc[j] + accl[j] * LOSC_INV + bb;
            zs[(mf << 4) + ((l >> 4) << 2) + j][colb] = tanhf(v);
        }
    }
    __syncthreads();
    if (tid < 256) {
        int p = tid >> 6;
        int gmp = p & 1, cp = p >> 1;
        half8 hv, lv;
        #pragma unroll
        for (int j = 0; j < 8; j++) {
            float v = zs[(gmp << 4) + (l & 15)][(cp << 5) + ((l >> 4) << 3) + j];
            half_t a, b; split16(v, a, b); hv[j] = a; lv[j] = b;
        }
        int base = ((((row0 >> 4) + gmp) * 16 + (col0 >> 5) + cp) * 64 + l) * 8;
        *(half8*)&t2h[base] = hv;
        *(half8*)&t2l[base] = lv;
    }
}

// Stage 3: vf = LN2(t2) @ W3^T + b3, h += dt * (vf contracted with spline dX).
// Block 32 rows x 256 cols, 512 threads (8 waves). Grid (16, 16).
__global__ __launch_bounds__(512) void stage3_kernel(
    const half_t* __restrict__ t2h, const half_t* __restrict__ t2l,
    const float* __restrict__ g2, const float* __restrict__ be2,
    const half_t* __restrict__ W3h, const half_t* __restrict__ W3l,
    const float* __restrict__ b3, const float* __restrict__ coeffs,
    float* __restrict__ hout, int ii, float frac)
{
    __shared__ __align__(16) half_t Ah[2 * 16 * 64 * 8];  // 32 KB
    __shared__ __align__(16) half_t Al[2 * 16 * 64 * 8];  // 32 KB
    __shared__ float part[1024];
    __shared__ float mr[32], rrs[32];
    __shared__ float dxs[32][17];
    const int tid = threadIdx.x, w = tid >> 6, l = tid & 63;
    const int row0 = blockIdx.x * 32, col0 = blockIdx.y * 256;
    const int gm = w & 1, cbase = (w >> 1) << 2;

    // spline derivative for this block's rows
    {
        int r = tid >> 4, d = tid & 15;
        int b = row0 + r;
        int base = (b * (L_ - 1) + ii) * 64 + d;
        float c1 = coeffs[base + 16], c2 = coeffs[base + 32], c3 = coeffs[base + 48];
        dxs[r][d] = c1 + 2.0f * frac * c2 + 3.0f * (frac * frac) * c3;
    }

    // pass 1: t2 values + stats
    float tv[32];
    {
        float s = 0.f, ss = 0.f;
        #pragma unroll
        for (int cc = 0; cc < 4; cc++) {
            int c = cbase + cc;
            int base = ((((row0 >> 4) + gm) * 16 + c) * 64 + l) * 8;
            half8 hv = *(const half8*)&t2h[base];
            half8 lv = *(const half8*)&t2l[base];
            #pragma unroll
            for (int j = 0; j < 8; j++) {
                float t = (float)hv[j] + (float)lv[j] * LOSC_INV;
                tv[(cc << 3) + j] = t;
                s += t; ss += t * t;
            }
        }
        part[w * 64 + l] = s;
        part[512 + w * 64 + l] = ss;
    }
    __syncthreads();
    if (tid < 32) {
        int r = tid, rgm = r >> 4;
        float s = 0.f, ss = 0.f;
        #pragma unroll
        for (int wi = 0; wi < 4; wi++) {
            int wv = rgm + (wi << 1);
            #pragma unroll
            for (int u = 0; u < 4; u++) {
                int idx = wv * 64 + (r & 15) + (u << 4);
                s += part[idx]; ss += part[512 + idx];
            }
        }
        float m = s * (1.f / 512.f);
        float var = ss * (1.f / 512.f) - m * m;
        mr[r] = m;
        rrs[r] = rsqrtf(var + 1e-5f);
    }
    __syncthreads();
    {
        int row = (gm << 4) + (l & 15);
        float m = mr[row], rv = rrs[row];
        #pragma unroll
        for (int cc = 0; cc < 4; cc++) {
            int c = cbase + cc;
            half8 hv, lv;
            #pragma unroll
            for (int j = 0; j < 8; j++) {
                int k = (c << 5) + ((l >> 4) << 3) + j;
                float val = (tv[(cc << 3) + j] - m) * rv * g2[k] + be2[k];
                half_t a, b; split16(val, a, b); hv[j] = a; lv[j] = b;
            }
            int base = (((gm << 4) + c) * 64 + l) * 8;
            *(half8*)&Ah[base] = hv;
            *(half8*)&Al[base] = lv;
        }
    }
    __syncthreads();

    // main: wave owns n-frags {2w, 2w+1}, both m-frags
    f32x4 acc[2][2], accl[2][2];
    #pragma unroll
    for (int a = 0; a < 2; a++)
        #pragma unroll
        for (int b = 0; b < 2; b++) { acc[a][b] = (f32x4){0.f,0.f,0.f,0.f}; accl[a][b] = (f32x4){0.f,0.f,0.f,0.f}; }

    for (int c = 0; c < 16; c++) {
        half8 ah0 = *(const half8*)&Ah[((c) * 64 + l) * 8];
        half8 al0 = *(const half8*)&Al[((c) * 64 + l) * 8];
        half8 ah1 = *(const half8*)&Ah[((16 + c) * 64 + l) * 8];
        half8 al1 = *(const half8*)&Al[((16 + c) * 64 + l) * 8];
        #pragma unroll
        for (int nfi = 0; nfi < 2; nfi++) {
            int gn = (col0 >> 4) + (w << 1) + nfi;
            half8 bh = *(const half8*)&W3h[(((gn << 4) + c) * 64 + l) * 8];
            half8 bl = *(const half8*)&W3l[(((gn << 4) + c) * 64 + l) * 8];
            acc[0][nfi]  = __builtin_amdgcn_mfma_f32_16x16x32_f16(ah0, bh, acc[0][nfi],  0, 0, 0);
            accl[0][nfi] = __builtin_amdgcn_mfma_f32_16x16x32_f16(ah0, bl, accl[0][nfi], 0, 0, 0);
            accl[0][nfi] = __builtin_amdgcn_mfma_f32_16x16x32_f16(al0, bh, accl[0][nfi], 0, 0, 0);
            acc[1][nfi]  = __builtin_amdgcn_mfma_f32_16x16x32_f16(ah1, bh, acc[1][nfi],  0, 0, 0);
            accl[1][nfi] = __builtin_amdgcn_mfma_f32_16x16x32_f16(ah1, bl, accl[1][nfi], 0, 0, 0);
            accl[1][nfi] = __builtin_amdgcn_mfma_f32_16x16x32_f16(al1, bh, accl[1][nfi], 0, 0, 0);
        }
    }

    // epilogue: + b3, contract with dX, 16-lane reduce, unique-writer h RMW
    const int d = l & 15;
    #pragma unroll
    for (int nfi = 0; nfi < 2; nfi++) {
        int hh = (col0 >> 4) + (w << 1) + nfi;
        float b3v = b3[(hh << 4) + d];
        #pragma unroll
        for (int mf = 0; mf < 2; mf++) {
            #pragma unroll
            for (int j = 0; j < 4; j++) {
                int rl = (mf << 4) + ((l >> 4) << 2) + j;
                float v = acc[mf][nfi][j] + accl[mf][nfi][j] * LOSC_INV + b3v;
                float s = v * dxs[rl][d];
                s += __shfl_xor(s, 1);
                s += __shfl_xor(s, 2);
                s += __shfl_xor(s, 4);
                s += __shfl_xor(s, 8);
                if (d == 0) hout[(row0 + rl) * H_ + hh] += s * DT_;
            }
        }
    }
}

// ---------------- launch ----------------

extern "C" void kernel_launch(void* const* d_in, const int* in_sizes, int n_in,
                              void* d_out, int out_size, void* d_ws, size_t ws_size,
                              hipStream_t stream) {
    const float* coeffs = (const float*)d_in[0];
    const float* W0  = (const float*)d_in[1];
    const float* b0  = (const float*)d_in[2];
    const float* W1  = (const float*)d_in[3];
    const float* b1  = (const float*)d_in[4];
    const float* g1  = (const float*)d_in[5];
    const float* be1 = (const float*)d_in[6];
    const float* W2  = (const float*)d_in[7];
    const float* b2  = (const float*)d_in[8];
    const float* g2  = (const float*)d_in[9];
    const float* be2 = (const float*)d_in[10];
    const float* W3  = (const float*)d_in[11];
    const float* b3  = (const float*)d_in[12];

    char* w = (char*)d_ws;
    float*  hbuf = (float*)(w);                       // 512 KB
    half_t* t1h  = (half_t*)(w + 512 * 1024);         // 512 KB
    half_t* t1l  = (half_t*)(w + 1024 * 1024);        // 512 KB
    half_t* t2h  = (half_t*)(w + 1536 * 1024);        // 512 KB
    half_t* t2l  = (half_t*)(w + 2048 * 1024);        // 512 KB
    half_t* W1h  = (half_t*)(w + 2560 * 1024);        // 256 KB
    half_t* W1l  = (half_t*)(w + 2816 * 1024);        // 256 KB
    half_t* W2h  = (half_t*)(w + 3072 * 1024);        // 512 KB
    half_t* W2l  = (half_t*)(w + 3584 * 1024);        // 512 KB
    half_t* W3h  = (half_t*)(w + 4096 * 1024);        // 4 MB
    half_t* W3l  = (half_t*)(w + 8192 * 1024);        // 4 MB  (total 12 MB)

    pack_frag_kernel<<<512, 256, 0, stream>>>(W1, W1h, W1l, 8, H_, V_ * H_);
    pack_frag_kernel<<<1024, 256, 0, stream>>>(W2, W2h, W2l, 16, V_, V_ * V_);
    pack_frag_kernel<<<8192, 256, 0, stream>>>(W3, W3h, W3l, 16, V_, (H_ * D_) * V_);
    h0_kernel<<<B_, H_, 0, stream>>>(coeffs, W0, b0, hbuf);

    for (int s = 0; s < STEPS_; s++) {
        float t = (float)s * 0.984375f;       // exact in fp32
        int ii = (int)t;
        if (ii > L_ - 2) ii = L_ - 2;
        float frac = t - (float)ii;
        gemm1_kernel<<<dim3(16, 8), 512, 0, stream>>>(hbuf, W1h, W1l, b1, t1h, t1l);
        gemm2_kernel<<<dim3(16, 8), 512, 0, stream>>>(t1h, t1l, g1, be1, W2h, W2l, b2, t2h, t2l);
        stage3_kernel<<<dim3(16, 16), 512, 0, stream>>>(t2h, t2l, g2, be2, W3h, W3l, b3,
                                                        coeffs, hbuf, ii, frac);
    }

    hipMemcpyAsync(d_out, hbuf, (size_t)B_ * H_ * sizeof(float),
                   hipMemcpyDeviceToDevice, stream);
}